// Round 18
// baseline (241.106 us; speedup 1.0000x reference)
//
#include <hip/hip_runtime.h>

#define DIM 64
#define K_CODES 512
#define N_VEC 131072
#define CREP 16
#define DREP 64
#define Q_OFF 1
#define PERP_OFF 8388609
#define ENC_OFF 8388610

#define DW_BLOCKS 512
#define ENC_BLOCKS 1792
#define QZ_BLOCKS 2048

using bfrag = __attribute__((ext_vector_type(8))) short;  // 8 bf16 = 4 VGPR
using ffrag = __attribute__((ext_vector_type(4))) float;  // 4 f32 acc

// Exact 3-way bf16 truncation split: x == x0 + x1 + x2.
__device__ __forceinline__ void split3(float x, short& h0, short& h1, short& h2)
{
    unsigned u0 = __float_as_uint(x);
    h0 = (short)(u0 >> 16);
    float r = x - __uint_as_float(u0 & 0xFFFF0000u);     // exact
    unsigned u1 = __float_as_uint(r);
    h1 = (short)(u1 >> 16);
    float r2 = r - __uint_as_float(u1 & 0xFFFF0000u);    // exact
    h2 = (short)(__float_as_uint(r2) >> 16);             // r2 fits bf16 exactly
}

// split 8 contiguous floats into three named bf16 fragments (no arrays).
__device__ __forceinline__ void split8(float4 va, float4 vb,
                                       bfrag& f0, bfrag& f1, bfrag& f2)
{
    short a, b, c;
    split3(va.x, a, b, c); f0[0] = a; f1[0] = b; f2[0] = c;
    split3(va.y, a, b, c); f0[1] = a; f1[1] = b; f2[1] = c;
    split3(va.z, a, b, c); f0[2] = a; f1[2] = b; f2[2] = c;
    split3(va.w, a, b, c); f0[3] = a; f1[3] = b; f2[3] = c;
    split3(vb.x, a, b, c); f0[4] = a; f1[4] = b; f2[4] = c;
    split3(vb.y, a, b, c); f0[5] = a; f1[5] = b; f2[5] = c;
    split3(vb.z, a, b, c); f0[6] = a; f1[6] = b; f2[6] = c;
    split3(vb.w, a, b, c); f0[7] = a; f1[7] = b; f2[7] = c;
}

// ---------------------------------------------------------------------------
// epack + ee fused, plus zeroing of crep / lossac / done-counter.
// epack[((ct*2+db)*3+s)*64+lane]: code c = ct*16+(lane&15),
// d = db*32+(lane>>4)*8+0..7, split s. 192 KB, L2-resident.
// ---------------------------------------------------------------------------
__global__ __launch_bounds__(256) void epack_ee_kernel(
    const float* __restrict__ emb_w,
    bfrag* __restrict__ epack,
    float* __restrict__ ee,
    float* __restrict__ crep,
    float* __restrict__ lossac)
{
    __shared__ float part[2][16][8];
    const int tl = threadIdx.x;
    const int t = blockIdx.x * 256 + tl;            // 0..4095
    const int lane = t & 63;
    const int db = (t >> 6) & 1;
    const int ctl = tl >> 7;                        // 0..1 (block-local)
    const int ct = t >> 7;                          // 0..31
    const int r16 = lane & 15, quad = lane >> 4;
    const int c  = ct * 16 + r16;
    const int d0 = db * 32 + quad * 8;
    const float* src = emb_w + (size_t)c * DIM + d0;

    crep[t] = 0.f;
    crep[4096 + t] = 0.f;
    if (t == 0) {
        lossac[0] = 0.f;                            // loss accumulator
        reinterpret_cast<unsigned*>(lossac)[1] = 0u; // qz done-counter
    }

    bfrag f0, f1, f2;
    float ssum = 0.f;
#pragma unroll
    for (int j = 0; j < 8; ++j) {
        const float x = src[j];
        ssum = fmaf(x, x, ssum);
        short a, b, cc;
        split3(x, a, b, cc);
        f0[j] = a; f1[j] = b; f2[j] = cc;
    }
    const int base = (ct * 2 + db) * 3;
    epack[(base + 0) * 64 + lane] = f0;
    epack[(base + 1) * 64 + lane] = f1;
    epack[(base + 2) * 64 + lane] = f2;

    part[ctl][r16][db * 4 + quad] = ssum;
    __syncthreads();
    if (tl < 32) {
        const int cl = tl >> 4, r = tl & 15;
        float s = 0.f;
#pragma unroll
        for (int i = 0; i < 8; ++i) s += part[cl][r][i];
        ee[(blockIdx.x * 2 + cl) * 16 + r] = s;
    }
}

// ---------------------------------------------------------------------------
// argmin via 6-pass split-bf16 MFMA -- FROZEN best-known config (R17).
// Wave owns 64 vectors; block = 4 waves = 256 vectors; grid 512.
// Writes idx + counts into 16 replicas; prologue zeroes dwrep slice.
// Tie rule: ascending-k scan + strict <, cross-lane prefers smaller k
// == numpy argmin (first minimum).
// ---------------------------------------------------------------------------

#define LOADXF(rt, db) { \
    const float* src_ = inputs + (v0 + rt * 16 + r16) * DIM + db * 32 + quad * 8; \
    const float4 va_ = *reinterpret_cast<const float4*>(src_); \
    const float4 vb_ = *reinterpret_cast<const float4*>(src_ + 4); \
    split8(va_, vb_, xf##rt##_##db##_0, xf##rt##_##db##_1, xf##rt##_##db##_2); }

#define MM(rt, db, sa, sb) \
    acc##rt = __builtin_amdgcn_mfma_f32_16x16x32_bf16( \
        xf##rt##_##db##_##sa, e_##db##_##sb, acc##rt, 0, 0, 0);

#define MMP(db, sa, sb) MM(0, db, sa, sb) MM(1, db, sa, sb) MM(2, db, sa, sb) MM(3, db, sa, sb)
#define MMALL(db) MMP(db,0,0) MMP(db,0,1) MMP(db,1,0) MMP(db,0,2) MMP(db,2,0) MMP(db,1,1)

#define UPD(rt, rg) { \
    const float dist_ = fmaf(-2.f, acc##rt[rg], eel); \
    if (dist_ < best##rt##_##rg) { best##rt##_##rg = dist_; bk##rt##_##rg = kc; } }

#define UPDALL(rt) UPD(rt,0) UPD(rt,1) UPD(rt,2) UPD(rt,3)

#define REDSTEP(b, k, m) { \
    const float ob_ = __shfl_xor(b, m, 64); const int ok_ = __shfl_xor(k, m, 64); \
    if (ob_ < b || (ob_ == b && ok_ < k)) { b = ob_; k = ok_; } }

#define RED(rt, rg) { \
    float b_ = best##rt##_##rg; int k_ = bk##rt##_##rg; \
    REDSTEP(b_, k_, 1) REDSTEP(b_, k_, 2) REDSTEP(b_, k_, 4) REDSTEP(b_, k_, 8) \
    bk##rt##_##rg = k_; }

#define EMIT(rt, rg) { \
    const int v_ = rt * 16 + quad * 4 + rg; \
    idx[v0 + v_] = bk##rt##_##rg; \
    atomicAdd(&crep[bk##rt##_##rg], 1.0f); }

__global__ __launch_bounds__(256, 2) void argmin_mfma_kernel(
    const float* __restrict__ inputs,
    const bfrag* __restrict__ epack,
    const float* __restrict__ eeg,
    int* __restrict__ idx,
    float* __restrict__ counts_rep,
    float* __restrict__ dwrep)
{
    const int t = threadIdx.x;
    const int lane = t & 63;
    const int r16 = lane & 15;
    const int quad = lane >> 4;
    const size_t v0 = (size_t)blockIdx.x * 256 + (t >> 6) * 64;

    // ---- zero this block's 16 KB slice of dwrep (8 MB / 512 blocks) ----
    {
        float4* z4 = reinterpret_cast<float4*>(dwrep) + (size_t)blockIdx.x * 1024;
        const float4 z = make_float4(0.f, 0.f, 0.f, 0.f);
#pragma unroll
        for (int i = 0; i < 4; ++i) z4[i * 256 + t] = z;
    }

    // ---- named A-fragments (24 bfrags = 96 VGPR, provably static) ----
    bfrag xf0_0_0, xf0_0_1, xf0_0_2, xf0_1_0, xf0_1_1, xf0_1_2;
    bfrag xf1_0_0, xf1_0_1, xf1_0_2, xf1_1_0, xf1_1_1, xf1_1_2;
    bfrag xf2_0_0, xf2_0_1, xf2_0_2, xf2_1_0, xf2_1_1, xf2_1_2;
    bfrag xf3_0_0, xf3_0_1, xf3_0_2, xf3_1_0, xf3_1_1, xf3_1_2;
    LOADXF(0,0) LOADXF(0,1) LOADXF(1,0) LOADXF(1,1)
    LOADXF(2,0) LOADXF(2,1) LOADXF(3,0) LOADXF(3,1)

    float best0_0 = 3.4e38f, best0_1 = 3.4e38f, best0_2 = 3.4e38f, best0_3 = 3.4e38f;
    float best1_0 = 3.4e38f, best1_1 = 3.4e38f, best1_2 = 3.4e38f, best1_3 = 3.4e38f;
    float best2_0 = 3.4e38f, best2_1 = 3.4e38f, best2_2 = 3.4e38f, best2_3 = 3.4e38f;
    float best3_0 = 3.4e38f, best3_1 = 3.4e38f, best3_2 = 3.4e38f, best3_3 = 3.4e38f;
    int bk0_0 = 0, bk0_1 = 0, bk0_2 = 0, bk0_3 = 0;
    int bk1_0 = 0, bk1_1 = 0, bk1_2 = 0, bk1_3 = 0;
    int bk2_0 = 0, bk2_1 = 0, bk2_2 = 0, bk2_3 = 0;
    int bk3_0 = 0, bk3_1 = 0, bk3_2 = 0, bk3_3 = 0;

#pragma unroll 2
    for (int ct = 0; ct < 32; ++ct) {
        // 6 B-fragment loads at constant offsets from one runtime base
        const bfrag* ep = epack + (size_t)ct * 384 + lane;
        const bfrag e_0_0 = ep[0];
        const bfrag e_0_1 = ep[64];
        const bfrag e_0_2 = ep[128];
        const bfrag e_1_0 = ep[192];
        const bfrag e_1_1 = ep[256];
        const bfrag e_1_2 = ep[320];
        const float eel = eeg[ct * 16 + r16];

        ffrag acc0 = (ffrag){0.f, 0.f, 0.f, 0.f};
        ffrag acc1 = (ffrag){0.f, 0.f, 0.f, 0.f};
        ffrag acc2 = (ffrag){0.f, 0.f, 0.f, 0.f};
        ffrag acc3 = (ffrag){0.f, 0.f, 0.f, 0.f};

        MMALL(0)
        MMALL(1)

        const int kc = ct * 16 + r16;
        UPDALL(0) UPDALL(1) UPDALL(2) UPDALL(3)
    }

    // ---- cross-lane argmin over each 16-lane code group ----
    RED(0,0) RED(0,1) RED(0,2) RED(0,3)
    RED(1,0) RED(1,1) RED(1,2) RED(1,3)
    RED(2,0) RED(2,1) RED(2,2) RED(2,3)
    RED(3,0) RED(3,1) RED(3,2) RED(3,3)

    if (r16 == 0) {
        float* crep = counts_rep + (blockIdx.x & (CREP - 1)) * K_CODES;
        EMIT(0,0) EMIT(0,1) EMIT(0,2) EMIT(0,3)
        EMIT(1,0) EMIT(1,1) EMIT(1,2) EMIT(1,3)
        EMIT(2,0) EMIT(2,1) EMIT(2,2) EMIT(2,3)
        EMIT(3,0) EMIT(3,1) EMIT(3,2) EMIT(3,3)
    }
}

// ---------------------------------------------------------------------------
// Uber kernel: enc one-hot full write (1792 blocks, grid-stride float4)
// CONCURRENT with dw segment-sum (512 blocks, 64-replica row atomics).
// ---------------------------------------------------------------------------
__global__ __launch_bounds__(256) void encdw_kernel(
    const float* __restrict__ inputs,
    const int* __restrict__ idx,
    float* __restrict__ enc,
    float* __restrict__ dwrep)
{
    const int bid = blockIdx.x;
    const int t = threadIdx.x;

    if (bid < DW_BLOCKS) {
        __shared__ int sIdx[256];
        const size_t vbase = (size_t)bid * 256;
        sIdx[t] = idx[vbase + t];
        __syncthreads();
        const int w = t >> 6, lane = t & 63;
        const int v0 = w * 64;
#pragma unroll 4
        for (int j = 0; j < 64; ++j) {
            const int v = v0 + j;
            const int k = sIdx[v];
            const float xv = inputs[(vbase + v) * DIM + lane];
            atomicAdd(&dwrep[((size_t)(v & (DREP - 1)) << 15) + (k << 6) + lane], xv);
        }
    } else {
        const int eb = bid - DW_BLOCKS;                    // 0..ENC_BLOCKS-1
        const size_t nf4 = 16777215;                       // (67108864-4)/4
        float4* body = reinterpret_cast<float4*>(enc + 2); // 16B-aligned
        const size_t stride = (size_t)ENC_BLOCKS * 256;

        for (size_t g = (size_t)eb * 256 + t; g < nf4; g += stride) {
            const size_t e0 = 4 * g + 2;                   // element index of .x
            const int r0 = (int)(e0 >> 9);
            const int r1 = (int)((e0 + 3) >> 9);
            const int i0 = idx[r0];
            const int i1 = (r1 != r0) ? idx[r1] : i0;
            float4 v;
            v.x = ((int)(e0 & 511) == i0) ? 1.f : 0.f;
            v.y = ((int)((e0 + 1) & 511) == (((e0 + 1) >> 9) == (size_t)r0 ? i0 : i1)) ? 1.f : 0.f;
            v.z = ((int)((e0 + 2) & 511) == (((e0 + 2) >> 9) == (size_t)r0 ? i0 : i1)) ? 1.f : 0.f;
            v.w = ((int)((e0 + 3) & 511) == (((e0 + 3) >> 9) == (size_t)r0 ? i0 : i1)) ? 1.f : 0.f;
            body[g] = v;
        }

        if (eb == 0 && t == 0) {
            const int k0 = idx[0];
            enc[0] = (k0 == 0) ? 1.f : 0.f;
            enc[1] = (k0 == 1) ? 1.f : 0.f;
            const int kL = idx[N_VEC - 1];
            enc[67108862] = (kL == 510) ? 1.f : 0.f;
            enc[67108863] = (kL == 511) ? 1.f : 0.f;
        }
    }
}

// ---------------------------------------------------------------------------
// emaBF (absorbs emaA): every block redundantly reduces the 16x512 counts
// replicas, builds all-512 smoothed cs in LDS, block 0 also writes
// perplexity. Then codebook update for its 4 codes. (Verified in R13.)
// ---------------------------------------------------------------------------
__global__ __launch_bounds__(256) void emaBF_kernel(
    const float* __restrict__ counts_rep,
    const float* __restrict__ ema_cs,
    const float* __restrict__ dwrep,
    const float* __restrict__ ema_w,
    float* __restrict__ new_emb,
    float* __restrict__ perp_out)
{
    __shared__ float scs[K_CODES];
    __shared__ float red[256];
    const int t = threadIdx.x;

    float c0 = 0.f, c1 = 0.f;
#pragma unroll
    for (int r = 0; r < CREP; ++r) {
        c0 += counts_rep[r * K_CODES + 2 * t];
        c1 += counts_rep[r * K_CODES + 2 * t + 1];
    }
    const float cs0 = ema_cs[2 * t] * 0.99f + 0.01f * c0;
    const float cs1 = ema_cs[2 * t + 1] * 0.99f + 0.01f * c1;

    red[t] = cs0 + cs1;
    __syncthreads();
    for (int s = 128; s > 0; s >>= 1) {
        if (t < s) red[t] += red[t + s];
        __syncthreads();
    }
    const float n = red[0];
    __syncthreads();

    const float scale = n / (n + (float)K_CODES * 1e-5f);
    scs[2 * t]     = (cs0 + 1e-5f) * scale;
    scs[2 * t + 1] = (cs1 + 1e-5f) * scale;

    if (blockIdx.x == 0) {
        const float p0 = c0 * (1.0f / (float)N_VEC);
        const float p1 = c1 * (1.0f / (float)N_VEC);
        red[t] = p0 * logf(p0 + 1e-10f) + p1 * logf(p1 + 1e-10f);
        __syncthreads();
        for (int s = 128; s > 0; s >>= 1) {
            if (t < s) red[t] += red[t + s];
            __syncthreads();
        }
        if (t == 0) perp_out[0] = expf(-red[0]);
    }
    __syncthreads();

    const int k = blockIdx.x * 4 + (t >> 6);
    const int e = k * DIM + (t & 63);
    float dwv = 0.f;
#pragma unroll
    for (int r = 0; r < DREP; ++r) dwv += dwrep[((size_t)r << 15) + e];
    const float v = ema_w[e] * 0.99f + 0.01f * dwv;
    new_emb[e] = v / scs[k];
}

// ---------------------------------------------------------------------------
// quantize + last-block finalize: gather + straight-through + NHWC->NCHW +
// commitment loss; the block that completes last writes out_loss.
// ---------------------------------------------------------------------------
__global__ __launch_bounds__(256) void quantize_kernel(
    const float* __restrict__ inputs,
    const int* __restrict__ idx,
    const float* __restrict__ new_emb,
    float* __restrict__ out_q,
    float* __restrict__ loss_accum,
    unsigned* __restrict__ done_ctr,
    float* __restrict__ out_loss)
{
    __shared__ int sIdx[64];
    __shared__ float tile[DIM][65];
    __shared__ float wsum[4];

    const int bh = blockIdx.x;
    const int b = bh >> 6, h = bh & 63;
    const int t = threadIdx.x;

    if (t < 64) sIdx[t] = idx[bh * 64 + t];
    __syncthreads();

    const float* inRow = inputs + (size_t)bh * 64 * DIM;
    const int d = t & 63;
    const int wg = t >> 6;
    float lsum = 0.f;
#pragma unroll
    for (int p = 0; p < 16; ++p) {
        const int w = wg * 16 + p;
        const float xv = inRow[w * DIM + d];
        const float qv = new_emb[sIdx[w] * DIM + d];
        const float diff = qv - xv;
        tile[d][w] = xv + diff;
        lsum = fmaf(diff, diff, lsum);
    }
    __syncthreads();

    const int w2 = t & 63;
    const int dg = t >> 6;
#pragma unroll
    for (int p = 0; p < 16; ++p) {
        const int d2 = dg * 16 + p;
        out_q[(((size_t)b * DIM + d2) * 64 + h) * 64 + w2] = tile[d2][w2];
    }

    for (int off = 32; off > 0; off >>= 1) lsum += __shfl_down(lsum, off);
    if ((t & 63) == 0) wsum[t >> 6] = lsum;
    __syncthreads();
    if (t == 0) {
        atomicAdd(loss_accum, (wsum[0] + wsum[1]) + (wsum[2] + wsum[3]));
        __threadfence();                         // our add visible before ctr
        const unsigned old = atomicAdd(done_ctr, 1u);
        if (old == QZ_BLOCKS - 1) {
            __threadfence();
            const float total = atomicAdd(loss_accum, 0.0f);  // L2-coherent read
            out_loss[0] = 0.25f * (total / 8388608.0f);
        }
    }
}

// ---------------------------------------------------------------------------
extern "C" void kernel_launch(void* const* d_in, const int* in_sizes, int n_in,
                              void* d_out, int out_size, void* d_ws, size_t ws_size,
                              hipStream_t stream)
{
    const float* inputs = (const float*)d_in[0];
    const float* emb_w  = (const float*)d_in[1];
    const float* ema_cs = (const float*)d_in[2];
    const float* ema_w  = (const float*)d_in[3];
    float* out = (float*)d_out;
    float* ws  = (float*)d_ws;

    // ws layout (f32 offsets):
    int*   idxbuf  = (int*)ws;              // [0, 131072)
    float* crep    = ws + 131072;           // [131072, 139264)  16x512
    float* lossac  = ws + 139264;           // [139264] loss, [139265] counter
    float* eebuf   = ws + 139777;           // [139777, 140289)
    float* nemb    = ws + 140289;           // [140289, 173057)
    bfrag* epack   = (bfrag*)(ws + 173060); // 192 KB, 16B-aligned

    // dw replicas (8 MB) in the not-yet-written quantized region of d_out
    // (out+16 -> 64B-aligned); zeroed by argmin, consumed by emaBF, then
    // overwritten by quantize.
    float* dwrep = out + 16;

    epack_ee_kernel<<<16, 256, 0, stream>>>(emb_w, epack, eebuf, crep, lossac);

    argmin_mfma_kernel<<<N_VEC / 256, 256, 0, stream>>>(
        inputs, epack, eebuf, idxbuf, crep, dwrep);

    encdw_kernel<<<DW_BLOCKS + ENC_BLOCKS, 256, 0, stream>>>(
        inputs, idxbuf, out + ENC_OFF, dwrep);

    emaBF_kernel<<<K_CODES / 4, 256, 0, stream>>>(
        crep, ema_cs, dwrep, ema_w, nemb, out + PERP_OFF);

    quantize_kernel<<<QZ_BLOCKS, 256, 0, stream>>>(
        inputs, idxbuf, nemb, out + Q_OFF, lossac,
        reinterpret_cast<unsigned*>(lossac + 1), out);
}

// Round 19
// 182.348 us; speedup vs baseline: 1.3222x; 1.3222x over previous
//
#include <hip/hip_runtime.h>

#define DIM 64
#define K_CODES 512
#define N_VEC 131072
#define CREP 16
#define DREP 64
#define Q_OFF 1
#define PERP_OFF 8388609
#define ENC_OFF 8388610

#define DW_BLOCKS 512
#define ENC_BLOCKS 1280
#define QZ_BLOCKS 2048

using bfrag = __attribute__((ext_vector_type(8))) short;  // 8 bf16 = 4 VGPR
using ffrag = __attribute__((ext_vector_type(4))) float;  // 4 f32 acc

// Exact 3-way bf16 truncation split: x == x0 + x1 + x2.
__device__ __forceinline__ void split3(float x, short& h0, short& h1, short& h2)
{
    unsigned u0 = __float_as_uint(x);
    h0 = (short)(u0 >> 16);
    float r = x - __uint_as_float(u0 & 0xFFFF0000u);     // exact
    unsigned u1 = __float_as_uint(r);
    h1 = (short)(u1 >> 16);
    float r2 = r - __uint_as_float(u1 & 0xFFFF0000u);    // exact
    h2 = (short)(__float_as_uint(r2) >> 16);             // r2 fits bf16 exactly
}

// split 8 contiguous floats into three named bf16 fragments (no arrays).
__device__ __forceinline__ void split8(float4 va, float4 vb,
                                       bfrag& f0, bfrag& f1, bfrag& f2)
{
    short a, b, c;
    split3(va.x, a, b, c); f0[0] = a; f1[0] = b; f2[0] = c;
    split3(va.y, a, b, c); f0[1] = a; f1[1] = b; f2[1] = c;
    split3(va.z, a, b, c); f0[2] = a; f1[2] = b; f2[2] = c;
    split3(va.w, a, b, c); f0[3] = a; f1[3] = b; f2[3] = c;
    split3(vb.x, a, b, c); f0[4] = a; f1[4] = b; f2[4] = c;
    split3(vb.y, a, b, c); f0[5] = a; f1[5] = b; f2[5] = c;
    split3(vb.z, a, b, c); f0[6] = a; f1[6] = b; f2[6] = c;
    split3(vb.w, a, b, c); f0[7] = a; f1[7] = b; f2[7] = c;
}

// ---------------------------------------------------------------------------
// epack + ee fused, plus zeroing of crep/lossac.
// epack[((ct*2+db)*3+s)*64+lane]: code c = ct*16+(lane&15),
// d = db*32+(lane>>4)*8+0..7, split s. 192 KB, L2-resident.
// ---------------------------------------------------------------------------
__global__ __launch_bounds__(256) void epack_ee_kernel(
    const float* __restrict__ emb_w,
    bfrag* __restrict__ epack,
    float* __restrict__ ee,
    float* __restrict__ crep,
    float* __restrict__ lossac)
{
    __shared__ float part[2][16][8];
    const int tl = threadIdx.x;
    const int t = blockIdx.x * 256 + tl;            // 0..4095
    const int lane = t & 63;
    const int db = (t >> 6) & 1;
    const int ctl = tl >> 7;                        // 0..1 (block-local)
    const int ct = t >> 7;                          // 0..31
    const int r16 = lane & 15, quad = lane >> 4;
    const int c  = ct * 16 + r16;
    const int d0 = db * 32 + quad * 8;
    const float* src = emb_w + (size_t)c * DIM + d0;

    crep[t] = 0.f;
    crep[4096 + t] = 0.f;
    if (t == 0) lossac[0] = 0.f;

    bfrag f0, f1, f2;
    float ssum = 0.f;
#pragma unroll
    for (int j = 0; j < 8; ++j) {
        const float x = src[j];
        ssum = fmaf(x, x, ssum);
        short a, b, cc;
        split3(x, a, b, cc);
        f0[j] = a; f1[j] = b; f2[j] = cc;
    }
    const int base = (ct * 2 + db) * 3;
    epack[(base + 0) * 64 + lane] = f0;
    epack[(base + 1) * 64 + lane] = f1;
    epack[(base + 2) * 64 + lane] = f2;

    part[ctl][r16][db * 4 + quad] = ssum;
    __syncthreads();
    if (tl < 32) {
        const int cl = tl >> 4, r = tl & 15;
        float s = 0.f;
#pragma unroll
        for (int i = 0; i < 8; ++i) s += part[cl][r][i];
        ee[(blockIdx.x * 2 + cl) * 16 + r] = s;
    }
}

// ---------------------------------------------------------------------------
// argmin via 6-pass split-bf16 MFMA -- FROZEN best-known config (R17).
// Wave owns 64 vectors; block = 4 waves = 256 vectors; grid 512.
// Writes idx + counts into 16 replicas; prologue zeroes dwrep slice.
// Tie rule: ascending-k scan + strict <, cross-lane prefers smaller k
// == numpy argmin (first minimum).
// ---------------------------------------------------------------------------

#define LOADXF(rt, db) { \
    const float* src_ = inputs + (v0 + rt * 16 + r16) * DIM + db * 32 + quad * 8; \
    const float4 va_ = *reinterpret_cast<const float4*>(src_); \
    const float4 vb_ = *reinterpret_cast<const float4*>(src_ + 4); \
    split8(va_, vb_, xf##rt##_##db##_0, xf##rt##_##db##_1, xf##rt##_##db##_2); }

#define MM(rt, db, sa, sb) \
    acc##rt = __builtin_amdgcn_mfma_f32_16x16x32_bf16( \
        xf##rt##_##db##_##sa, e_##db##_##sb, acc##rt, 0, 0, 0);

#define MMP(db, sa, sb) MM(0, db, sa, sb) MM(1, db, sa, sb) MM(2, db, sa, sb) MM(3, db, sa, sb)
#define MMALL(db) MMP(db,0,0) MMP(db,0,1) MMP(db,1,0) MMP(db,0,2) MMP(db,2,0) MMP(db,1,1)

#define UPD(rt, rg) { \
    const float dist_ = fmaf(-2.f, acc##rt[rg], eel); \
    if (dist_ < best##rt##_##rg) { best##rt##_##rg = dist_; bk##rt##_##rg = kc; } }

#define UPDALL(rt) UPD(rt,0) UPD(rt,1) UPD(rt,2) UPD(rt,3)

#define REDSTEP(b, k, m) { \
    const float ob_ = __shfl_xor(b, m, 64); const int ok_ = __shfl_xor(k, m, 64); \
    if (ob_ < b || (ob_ == b && ok_ < k)) { b = ob_; k = ok_; } }

#define RED(rt, rg) { \
    float b_ = best##rt##_##rg; int k_ = bk##rt##_##rg; \
    REDSTEP(b_, k_, 1) REDSTEP(b_, k_, 2) REDSTEP(b_, k_, 4) REDSTEP(b_, k_, 8) \
    bk##rt##_##rg = k_; }

#define EMIT(rt, rg) { \
    const int v_ = rt * 16 + quad * 4 + rg; \
    idx[v0 + v_] = bk##rt##_##rg; \
    atomicAdd(&crep[bk##rt##_##rg], 1.0f); }

__global__ __launch_bounds__(256, 2) void argmin_mfma_kernel(
    const float* __restrict__ inputs,
    const bfrag* __restrict__ epack,
    const float* __restrict__ eeg,
    int* __restrict__ idx,
    float* __restrict__ counts_rep,
    float* __restrict__ dwrep)
{
    const int t = threadIdx.x;
    const int lane = t & 63;
    const int r16 = lane & 15;
    const int quad = lane >> 4;
    const size_t v0 = (size_t)blockIdx.x * 256 + (t >> 6) * 64;

    // ---- zero this block's 16 KB slice of dwrep (8 MB / 512 blocks) ----
    {
        float4* z4 = reinterpret_cast<float4*>(dwrep) + (size_t)blockIdx.x * 1024;
        const float4 z = make_float4(0.f, 0.f, 0.f, 0.f);
#pragma unroll
        for (int i = 0; i < 4; ++i) z4[i * 256 + t] = z;
    }

    // ---- named A-fragments (24 bfrags = 96 VGPR, provably static) ----
    bfrag xf0_0_0, xf0_0_1, xf0_0_2, xf0_1_0, xf0_1_1, xf0_1_2;
    bfrag xf1_0_0, xf1_0_1, xf1_0_2, xf1_1_0, xf1_1_1, xf1_1_2;
    bfrag xf2_0_0, xf2_0_1, xf2_0_2, xf2_1_0, xf2_1_1, xf2_1_2;
    bfrag xf3_0_0, xf3_0_1, xf3_0_2, xf3_1_0, xf3_1_1, xf3_1_2;
    LOADXF(0,0) LOADXF(0,1) LOADXF(1,0) LOADXF(1,1)
    LOADXF(2,0) LOADXF(2,1) LOADXF(3,0) LOADXF(3,1)

    float best0_0 = 3.4e38f, best0_1 = 3.4e38f, best0_2 = 3.4e38f, best0_3 = 3.4e38f;
    float best1_0 = 3.4e38f, best1_1 = 3.4e38f, best1_2 = 3.4e38f, best1_3 = 3.4e38f;
    float best2_0 = 3.4e38f, best2_1 = 3.4e38f, best2_2 = 3.4e38f, best2_3 = 3.4e38f;
    float best3_0 = 3.4e38f, best3_1 = 3.4e38f, best3_2 = 3.4e38f, best3_3 = 3.4e38f;
    int bk0_0 = 0, bk0_1 = 0, bk0_2 = 0, bk0_3 = 0;
    int bk1_0 = 0, bk1_1 = 0, bk1_2 = 0, bk1_3 = 0;
    int bk2_0 = 0, bk2_1 = 0, bk2_2 = 0, bk2_3 = 0;
    int bk3_0 = 0, bk3_1 = 0, bk3_2 = 0, bk3_3 = 0;

#pragma unroll 2
    for (int ct = 0; ct < 32; ++ct) {
        // 6 B-fragment loads at constant offsets from one runtime base
        const bfrag* ep = epack + (size_t)ct * 384 + lane;
        const bfrag e_0_0 = ep[0];
        const bfrag e_0_1 = ep[64];
        const bfrag e_0_2 = ep[128];
        const bfrag e_1_0 = ep[192];
        const bfrag e_1_1 = ep[256];
        const bfrag e_1_2 = ep[320];
        const float eel = eeg[ct * 16 + r16];

        ffrag acc0 = (ffrag){0.f, 0.f, 0.f, 0.f};
        ffrag acc1 = (ffrag){0.f, 0.f, 0.f, 0.f};
        ffrag acc2 = (ffrag){0.f, 0.f, 0.f, 0.f};
        ffrag acc3 = (ffrag){0.f, 0.f, 0.f, 0.f};

        MMALL(0)
        MMALL(1)

        const int kc = ct * 16 + r16;
        UPDALL(0) UPDALL(1) UPDALL(2) UPDALL(3)
    }

    // ---- cross-lane argmin over each 16-lane code group ----
    RED(0,0) RED(0,1) RED(0,2) RED(0,3)
    RED(1,0) RED(1,1) RED(1,2) RED(1,3)
    RED(2,0) RED(2,1) RED(2,2) RED(2,3)
    RED(3,0) RED(3,1) RED(3,2) RED(3,3)

    if (r16 == 0) {
        float* crep = counts_rep + (blockIdx.x & (CREP - 1)) * K_CODES;
        EMIT(0,0) EMIT(0,1) EMIT(0,2) EMIT(0,3)
        EMIT(1,0) EMIT(1,1) EMIT(1,2) EMIT(1,3)
        EMIT(2,0) EMIT(2,1) EMIT(2,2) EMIT(2,3)
        EMIT(3,0) EMIT(3,1) EMIT(3,2) EMIT(3,3)
    }
}

// ---------------------------------------------------------------------------
// Uber kernel: enc one-hot full write (1280 blocks, grid-stride float4)
// CONCURRENT with dw segment-sum (512 blocks, 64-replica row atomics).
// ---------------------------------------------------------------------------
__global__ __launch_bounds__(256) void encdw_kernel(
    const float* __restrict__ inputs,
    const int* __restrict__ idx,
    float* __restrict__ enc,
    float* __restrict__ dwrep)
{
    const int bid = blockIdx.x;
    const int t = threadIdx.x;

    if (bid < DW_BLOCKS) {
        __shared__ int sIdx[256];
        const size_t vbase = (size_t)bid * 256;
        sIdx[t] = idx[vbase + t];
        __syncthreads();
        const int w = t >> 6, lane = t & 63;
        const int v0 = w * 64;
#pragma unroll 4
        for (int j = 0; j < 64; ++j) {
            const int v = v0 + j;
            const int k = sIdx[v];
            const float xv = inputs[(vbase + v) * DIM + lane];
            atomicAdd(&dwrep[((size_t)(v & (DREP - 1)) << 15) + (k << 6) + lane], xv);
        }
    } else {
        const int eb = bid - DW_BLOCKS;                    // 0..ENC_BLOCKS-1
        const size_t nf4 = 16777215;                       // (67108864-4)/4
        float4* body = reinterpret_cast<float4*>(enc + 2); // 16B-aligned
        const size_t stride = (size_t)ENC_BLOCKS * 256;

        for (size_t g = (size_t)eb * 256 + t; g < nf4; g += stride) {
            const size_t e0 = 4 * g + 2;                   // element index of .x
            const int r0 = (int)(e0 >> 9);
            const int r1 = (int)((e0 + 3) >> 9);
            const int i0 = idx[r0];
            const int i1 = (r1 != r0) ? idx[r1] : i0;
            float4 v;
            v.x = ((int)(e0 & 511) == i0) ? 1.f : 0.f;
            v.y = ((int)((e0 + 1) & 511) == (((e0 + 1) >> 9) == (size_t)r0 ? i0 : i1)) ? 1.f : 0.f;
            v.z = ((int)((e0 + 2) & 511) == (((e0 + 2) >> 9) == (size_t)r0 ? i0 : i1)) ? 1.f : 0.f;
            v.w = ((int)((e0 + 3) & 511) == (((e0 + 3) >> 9) == (size_t)r0 ? i0 : i1)) ? 1.f : 0.f;
            body[g] = v;
        }

        if (eb == 0 && t == 0) {
            const int k0 = idx[0];
            enc[0] = (k0 == 0) ? 1.f : 0.f;
            enc[1] = (k0 == 1) ? 1.f : 0.f;
            const int kL = idx[N_VEC - 1];
            enc[67108862] = (kL == 510) ? 1.f : 0.f;
            enc[67108863] = (kL == 511) ? 1.f : 0.f;
        }
    }
}

// ---------------------------------------------------------------------------
// emaA: counts replica-reduce + EMA cluster size + Laplace + perplexity.
// ---------------------------------------------------------------------------
__global__ __launch_bounds__(512) void emaA_kernel(
    const float* __restrict__ counts_rep,
    const float* __restrict__ ema_cs,
    float* __restrict__ csbuf,
    float* __restrict__ perp_out)
{
    __shared__ float red[K_CODES];
    const int k = threadIdx.x;
    float cnt = 0.f;
#pragma unroll
    for (int r = 0; r < CREP; ++r) cnt += counts_rep[r * K_CODES + k];
    float cs = ema_cs[k] * 0.99f + 0.01f * cnt;

    red[k] = cs;
    __syncthreads();
    for (int s = K_CODES / 2; s > 0; s >>= 1) {
        if (k < s) red[k] += red[k + s];
        __syncthreads();
    }
    const float n = red[0];
    __syncthreads();

    csbuf[k] = (cs + 1e-5f) / (n + (float)K_CODES * 1e-5f) * n;

    const float p = cnt * (1.0f / (float)N_VEC);
    red[k] = p * logf(p + 1e-10f);
    __syncthreads();
    for (int s = K_CODES / 2; s > 0; s >>= 1) {
        if (k < s) red[k] += red[k + s];
        __syncthreads();
    }
    if (k == 0) perp_out[0] = expf(-red[0]);
}

// ---------------------------------------------------------------------------
// emaB: dw replica-reduce + codebook update. 32768 (k,d) threads.
// ---------------------------------------------------------------------------
__global__ __launch_bounds__(256) void emaB_kernel(
    const float* __restrict__ dwrep,
    const float* __restrict__ ema_w,
    const float* __restrict__ csbuf,
    float* __restrict__ new_emb)
{
    const int t = blockIdx.x * 256 + threadIdx.x;   // 0..32767 = k*64+d
    const int k = t >> 6;
    float dwv = 0.f;
#pragma unroll
    for (int r = 0; r < DREP; ++r) dwv += dwrep[((size_t)r << 15) + t];
    const float v = ema_w[t] * 0.99f + 0.01f * dwv;
    new_emb[t] = v / csbuf[k];
}

// ---------------------------------------------------------------------------
// quantize: gather + straight-through + NHWC->NCHW + commitment loss.
// ---------------------------------------------------------------------------
__global__ __launch_bounds__(256) void quantize_kernel(
    const float* __restrict__ inputs,
    const int* __restrict__ idx,
    const float* __restrict__ new_emb,
    float* __restrict__ out_q,
    float* __restrict__ loss_accum)
{
    __shared__ int sIdx[64];
    __shared__ float tile[DIM][65];
    __shared__ float wsum[4];

    const int bh = blockIdx.x;
    const int b = bh >> 6, h = bh & 63;
    const int t = threadIdx.x;

    if (t < 64) sIdx[t] = idx[bh * 64 + t];
    __syncthreads();

    const float* inRow = inputs + (size_t)bh * 64 * DIM;
    const int d = t & 63;
    const int wg = t >> 6;
    float lsum = 0.f;
#pragma unroll
    for (int p = 0; p < 16; ++p) {
        const int w = wg * 16 + p;
        const float xv = inRow[w * DIM + d];
        const float qv = new_emb[sIdx[w] * DIM + d];
        const float diff = qv - xv;
        tile[d][w] = xv + diff;
        lsum = fmaf(diff, diff, lsum);
    }
    __syncthreads();

    const int w2 = t & 63;
    const int dg = t >> 6;
#pragma unroll
    for (int p = 0; p < 16; ++p) {
        const int d2 = dg * 16 + p;
        out_q[(((size_t)b * DIM + d2) * 64 + h) * 64 + w2] = tile[d2][w2];
    }

    for (int off = 32; off > 0; off >>= 1) lsum += __shfl_down(lsum, off);
    if ((t & 63) == 0) wsum[t >> 6] = lsum;
    __syncthreads();
    if (t == 0) atomicAdd(loss_accum, (wsum[0] + wsum[1]) + (wsum[2] + wsum[3]));
}

__global__ void finalize_kernel(const float* __restrict__ loss_accum,
                                float* __restrict__ out_loss)
{
    out_loss[0] = 0.25f * (loss_accum[0] / 8388608.0f);
}

// ---------------------------------------------------------------------------
extern "C" void kernel_launch(void* const* d_in, const int* in_sizes, int n_in,
                              void* d_out, int out_size, void* d_ws, size_t ws_size,
                              hipStream_t stream)
{
    const float* inputs = (const float*)d_in[0];
    const float* emb_w  = (const float*)d_in[1];
    const float* ema_cs = (const float*)d_in[2];
    const float* ema_w  = (const float*)d_in[3];
    float* out = (float*)d_out;
    float* ws  = (float*)d_ws;

    // ws layout (f32 offsets):
    int*   idxbuf  = (int*)ws;              // [0, 131072)
    float* crep    = ws + 131072;           // [131072, 139264)  16x512
    float* lossac  = ws + 139264;           // [139264]
    float* csbuf   = ws + 139265;           // [139265, 139777)
    float* eebuf   = ws + 139777;           // [139777, 140289)
    float* nemb    = ws + 140289;           // [140289, 173057)
    bfrag* epack   = (bfrag*)(ws + 173060); // 192 KB, 16B-aligned

    // dw replicas (8 MB) in the not-yet-written quantized region of d_out
    // (out+16 -> 64B-aligned); zeroed by argmin, consumed by emaB, then
    // overwritten by quantize.
    float* dwrep = out + 16;

    epack_ee_kernel<<<16, 256, 0, stream>>>(emb_w, epack, eebuf, crep, lossac);

    argmin_mfma_kernel<<<N_VEC / 256, 256, 0, stream>>>(
        inputs, epack, eebuf, idxbuf, crep, dwrep);

    encdw_kernel<<<DW_BLOCKS + ENC_BLOCKS, 256, 0, stream>>>(
        inputs, idxbuf, out + ENC_OFF, dwrep);

    emaA_kernel<<<1, K_CODES, 0, stream>>>(crep, ema_cs, csbuf, out + PERP_OFF);
    emaB_kernel<<<K_CODES * DIM / 256, 256, 0, stream>>>(dwrep, ema_w, csbuf, nemb);

    quantize_kernel<<<QZ_BLOCKS, 256, 0, stream>>>(
        inputs, idxbuf, nemb, out + Q_OFF, lossac);

    finalize_kernel<<<1, 1, 0, stream>>>(lossac, out);
}

// Round 20
// 182.289 us; speedup vs baseline: 1.3227x; 1.0003x over previous
//
#include <hip/hip_runtime.h>

#define DIM 64
#define K_CODES 512
#define N_VEC 131072
#define CREP 16
#define DREP 64
#define Q_OFF 1
#define PERP_OFF 8388609
#define ENC_OFF 8388610

#define DW_BLOCKS 512
#define ENC_BLOCKS 1280
#define QZ_BLOCKS 2048

using bfrag = __attribute__((ext_vector_type(8))) short;  // 8 bf16 = 4 VGPR
using ffrag = __attribute__((ext_vector_type(4))) float;  // 4 f32 acc

// Exact 3-way bf16 truncation split: x == x0 + x1 + x2.
__device__ __forceinline__ void split3(float x, short& h0, short& h1, short& h2)
{
    unsigned u0 = __float_as_uint(x);
    h0 = (short)(u0 >> 16);
    float r = x - __uint_as_float(u0 & 0xFFFF0000u);     // exact
    unsigned u1 = __float_as_uint(r);
    h1 = (short)(u1 >> 16);
    float r2 = r - __uint_as_float(u1 & 0xFFFF0000u);    // exact
    h2 = (short)(__float_as_uint(r2) >> 16);             // r2 fits bf16 exactly
}

// ---------------------------------------------------------------------------
// epack + ee fused, plus zeroing of crep/lossac.
// epack[((ct*2+db)*3+s)*64+lane]: code c = ct*16+(lane&15),
// d = db*32+(lane>>4)*8+0..7, split s. 192 KB, L2-resident.
// ---------------------------------------------------------------------------
__global__ __launch_bounds__(256) void epack_ee_kernel(
    const float* __restrict__ emb_w,
    bfrag* __restrict__ epack,
    float* __restrict__ ee,
    float* __restrict__ crep,
    float* __restrict__ lossac)
{
    __shared__ float part[2][16][8];
    const int tl = threadIdx.x;
    const int t = blockIdx.x * 256 + tl;            // 0..4095
    const int lane = t & 63;
    const int db = (t >> 6) & 1;
    const int ctl = tl >> 7;                        // 0..1 (block-local)
    const int ct = t >> 7;                          // 0..31
    const int r16 = lane & 15, quad = lane >> 4;
    const int c  = ct * 16 + r16;
    const int d0 = db * 32 + quad * 8;
    const float* src = emb_w + (size_t)c * DIM + d0;

    crep[t] = 0.f;
    crep[4096 + t] = 0.f;
    if (t == 0) lossac[0] = 0.f;

    bfrag f0, f1, f2;
    float ssum = 0.f;
#pragma unroll
    for (int j = 0; j < 8; ++j) {
        const float x = src[j];
        ssum = fmaf(x, x, ssum);
        short a, b, cc;
        split3(x, a, b, cc);
        f0[j] = a; f1[j] = b; f2[j] = cc;
    }
    const int base = (ct * 2 + db) * 3;
    epack[(base + 0) * 64 + lane] = f0;
    epack[(base + 1) * 64 + lane] = f1;
    epack[(base + 2) * 64 + lane] = f2;

    part[ctl][r16][db * 4 + quad] = ssum;
    __syncthreads();
    if (tl < 32) {
        const int cl = tl >> 4, r = tl & 15;
        float s = 0.f;
#pragma unroll
        for (int i = 0; i < 8; ++i) s += part[cl][r][i];
        ee[(blockIdx.x * 2 + cl) * 16 + r] = s;
    }
}

// ---------------------------------------------------------------------------
// argmin via 6-pass split-bf16 MFMA. TLP experiment: wave owns 32 vectors
// (2 row-tiles), live set ~110 VGPR, (256,4) -> 4 waves/SIMD (2x the R19
// TLP), grid 1024. Costs 2x epack L2 re-reads; wins if latency-bound.
// Writes idx + counts into 16 replicas; prologue zeroes dwrep slice.
// Tie rule: ascending-k scan + strict <, cross-lane prefers smaller k
// == numpy argmin (first minimum).
// ---------------------------------------------------------------------------
__global__ __launch_bounds__(256, 4) void argmin_mfma_kernel(
    const float* __restrict__ inputs,
    const bfrag* __restrict__ epack,
    const float* __restrict__ eeg,
    int* __restrict__ idx,
    float* __restrict__ counts_rep,
    float* __restrict__ dwrep)
{
    const int t = threadIdx.x;
    const int lane = t & 63;
    const int r16 = lane & 15;
    const int quad = lane >> 4;
    const size_t v0 = (size_t)blockIdx.x * 128 + (t >> 6) * 32;

    // ---- zero this block's 8 KB slice of dwrep (8 MB / 1024 blocks) ----
    {
        float4* z4 = reinterpret_cast<float4*>(dwrep) + (size_t)blockIdx.x * 512;
        const float4 z = make_float4(0.f, 0.f, 0.f, 0.f);
#pragma unroll
        for (int i = 0; i < 2; ++i) z4[i * 256 + t] = z;
    }

    // ---- load + exact-split X into A-fragments (48 VGPRs) ----
    bfrag xf[2][2][3];
#pragma unroll
    for (int rt = 0; rt < 2; ++rt)
#pragma unroll
        for (int db = 0; db < 2; ++db) {
            const float* src = inputs + (v0 + rt * 16 + r16) * DIM + db * 32 + quad * 8;
            const float4 va = *reinterpret_cast<const float4*>(src);
            const float4 vb = *reinterpret_cast<const float4*>(src + 4);
            float vals[8] = {va.x, va.y, va.z, va.w, vb.x, vb.y, vb.z, vb.w};
            bfrag f0, f1, f2;
#pragma unroll
            for (int j = 0; j < 8; ++j) {
                short a, b, c;
                split3(vals[j], a, b, c);
                f0[j] = a; f1[j] = b; f2[j] = c;
            }
            xf[rt][db][0] = f0; xf[rt][db][1] = f1; xf[rt][db][2] = f2;
        }

    float best[2][4];
    int bestk[2][4];
#pragma unroll
    for (int a = 0; a < 2; ++a)
#pragma unroll
        for (int b = 0; b < 4; ++b) { best[a][b] = 3.4e38f; bestk[a][b] = 0; }

    constexpr int PI[6] = {0, 0, 1, 0, 2, 1};
    constexpr int PJ[6] = {0, 1, 0, 2, 0, 1};

#pragma unroll 2
    for (int ct = 0; ct < 32; ++ct) {
        const bfrag* ep = epack + (size_t)ct * 384 + lane;
        bfrag e[2][3];
#pragma unroll
        for (int db = 0; db < 2; ++db)
#pragma unroll
            for (int s = 0; s < 3; ++s)
                e[db][s] = ep[(db * 3 + s) * 64];
        const float eel = eeg[ct * 16 + r16];

        ffrag acc[2];
        acc[0] = (ffrag){0.f, 0.f, 0.f, 0.f};
        acc[1] = (ffrag){0.f, 0.f, 0.f, 0.f};
#pragma unroll
        for (int db = 0; db < 2; ++db)
#pragma unroll
            for (int p = 0; p < 6; ++p) {
                acc[0] = __builtin_amdgcn_mfma_f32_16x16x32_bf16(
                    xf[0][db][PI[p]], e[db][PJ[p]], acc[0], 0, 0, 0);
                acc[1] = __builtin_amdgcn_mfma_f32_16x16x32_bf16(
                    xf[1][db][PI[p]], e[db][PJ[p]], acc[1], 0, 0, 0);
            }

        const int kc = ct * 16 + r16;
#pragma unroll
        for (int rt = 0; rt < 2; ++rt)
#pragma unroll
            for (int rg = 0; rg < 4; ++rg) {
                const float dist = fmaf(-2.f, acc[rt][rg], eel);
                if (dist < best[rt][rg]) { best[rt][rg] = dist; bestk[rt][rg] = kc; }
            }
    }

    // ---- cross-lane argmin over each 16-lane code group ----
#pragma unroll
    for (int rt = 0; rt < 2; ++rt)
#pragma unroll
        for (int rg = 0; rg < 4; ++rg) {
            float b = best[rt][rg];
            int k = bestk[rt][rg];
#pragma unroll
            for (int m = 1; m < 16; m <<= 1) {
                const float ob = __shfl_xor(b, m, 64);
                const int ok = __shfl_xor(k, m, 64);
                if (ob < b || (ob == b && ok < k)) { b = ob; k = ok; }
            }
            bestk[rt][rg] = k;
        }

    if (r16 == 0) {
        float* crep = counts_rep + (blockIdx.x & (CREP - 1)) * K_CODES;
#pragma unroll
        for (int rt = 0; rt < 2; ++rt)
#pragma unroll
            for (int rg = 0; rg < 4; ++rg) {
                const int v = rt * 16 + quad * 4 + rg;
                const int k = bestk[rt][rg];
                idx[v0 + v] = k;
                atomicAdd(&crep[k], 1.0f);
            }
    }
}

// ---------------------------------------------------------------------------
// Uber kernel: enc one-hot full write (1280 blocks, grid-stride float4)
// CONCURRENT with dw segment-sum (512 blocks, 64-replica row atomics).
// ---------------------------------------------------------------------------
__global__ __launch_bounds__(256) void encdw_kernel(
    const float* __restrict__ inputs,
    const int* __restrict__ idx,
    float* __restrict__ enc,
    float* __restrict__ dwrep)
{
    const int bid = blockIdx.x;
    const int t = threadIdx.x;

    if (bid < DW_BLOCKS) {
        __shared__ int sIdx[256];
        const size_t vbase = (size_t)bid * 256;
        sIdx[t] = idx[vbase + t];
        __syncthreads();
        const int w = t >> 6, lane = t & 63;
        const int v0 = w * 64;
#pragma unroll 4
        for (int j = 0; j < 64; ++j) {
            const int v = v0 + j;
            const int k = sIdx[v];
            const float xv = inputs[(vbase + v) * DIM + lane];
            atomicAdd(&dwrep[((size_t)(v & (DREP - 1)) << 15) + (k << 6) + lane], xv);
        }
    } else {
        const int eb = bid - DW_BLOCKS;                    // 0..ENC_BLOCKS-1
        const size_t nf4 = 16777215;                       // (67108864-4)/4
        float4* body = reinterpret_cast<float4*>(enc + 2); // 16B-aligned
        const size_t stride = (size_t)ENC_BLOCKS * 256;

        for (size_t g = (size_t)eb * 256 + t; g < nf4; g += stride) {
            const size_t e0 = 4 * g + 2;                   // element index of .x
            const int r0 = (int)(e0 >> 9);
            const int r1 = (int)((e0 + 3) >> 9);
            const int i0 = idx[r0];
            const int i1 = (r1 != r0) ? idx[r1] : i0;
            float4 v;
            v.x = ((int)(e0 & 511) == i0) ? 1.f : 0.f;
            v.y = ((int)((e0 + 1) & 511) == (((e0 + 1) >> 9) == (size_t)r0 ? i0 : i1)) ? 1.f : 0.f;
            v.z = ((int)((e0 + 2) & 511) == (((e0 + 2) >> 9) == (size_t)r0 ? i0 : i1)) ? 1.f : 0.f;
            v.w = ((int)((e0 + 3) & 511) == (((e0 + 3) >> 9) == (size_t)r0 ? i0 : i1)) ? 1.f : 0.f;
            body[g] = v;
        }

        if (eb == 0 && t == 0) {
            const int k0 = idx[0];
            enc[0] = (k0 == 0) ? 1.f : 0.f;
            enc[1] = (k0 == 1) ? 1.f : 0.f;
            const int kL = idx[N_VEC - 1];
            enc[67108862] = (kL == 510) ? 1.f : 0.f;
            enc[67108863] = (kL == 511) ? 1.f : 0.f;
        }
    }
}

// ---------------------------------------------------------------------------
// emaA: counts replica-reduce + EMA cluster size + Laplace + perplexity.
// ---------------------------------------------------------------------------
__global__ __launch_bounds__(512) void emaA_kernel(
    const float* __restrict__ counts_rep,
    const float* __restrict__ ema_cs,
    float* __restrict__ csbuf,
    float* __restrict__ perp_out)
{
    __shared__ float red[K_CODES];
    const int k = threadIdx.x;
    float cnt = 0.f;
#pragma unroll
    for (int r = 0; r < CREP; ++r) cnt += counts_rep[r * K_CODES + k];
    float cs = ema_cs[k] * 0.99f + 0.01f * cnt;

    red[k] = cs;
    __syncthreads();
    for (int s = K_CODES / 2; s > 0; s >>= 1) {
        if (k < s) red[k] += red[k + s];
        __syncthreads();
    }
    const float n = red[0];
    __syncthreads();

    csbuf[k] = (cs + 1e-5f) / (n + (float)K_CODES * 1e-5f) * n;

    const float p = cnt * (1.0f / (float)N_VEC);
    red[k] = p * logf(p + 1e-10f);
    __syncthreads();
    for (int s = K_CODES / 2; s > 0; s >>= 1) {
        if (k < s) red[k] += red[k + s];
        __syncthreads();
    }
    if (k == 0) perp_out[0] = expf(-red[0]);
}

// ---------------------------------------------------------------------------
// emaB: dw replica-reduce + codebook update. 32768 (k,d) threads.
// ---------------------------------------------------------------------------
__global__ __launch_bounds__(256) void emaB_kernel(
    const float* __restrict__ dwrep,
    const float* __restrict__ ema_w,
    const float* __restrict__ csbuf,
    float* __restrict__ new_emb)
{
    const int t = blockIdx.x * 256 + threadIdx.x;   // 0..32767 = k*64+d
    const int k = t >> 6;
    float dwv = 0.f;
#pragma unroll
    for (int r = 0; r < DREP; ++r) dwv += dwrep[((size_t)r << 15) + t];
    const float v = ema_w[t] * 0.99f + 0.01f * dwv;
    new_emb[t] = v / csbuf[k];
}

// ---------------------------------------------------------------------------
// quantize: gather + straight-through + NHWC->NCHW + commitment loss.
// ---------------------------------------------------------------------------
__global__ __launch_bounds__(256) void quantize_kernel(
    const float* __restrict__ inputs,
    const int* __restrict__ idx,
    const float* __restrict__ new_emb,
    float* __restrict__ out_q,
    float* __restrict__ loss_accum)
{
    __shared__ int sIdx[64];
    __shared__ float tile[DIM][65];
    __shared__ float wsum[4];

    const int bh = blockIdx.x;
    const int b = bh >> 6, h = bh & 63;
    const int t = threadIdx.x;

    if (t < 64) sIdx[t] = idx[bh * 64 + t];
    __syncthreads();

    const float* inRow = inputs + (size_t)bh * 64 * DIM;
    const int d = t & 63;
    const int wg = t >> 6;
    float lsum = 0.f;
#pragma unroll
    for (int p = 0; p < 16; ++p) {
        const int w = wg * 16 + p;
        const float xv = inRow[w * DIM + d];
        const float qv = new_emb[sIdx[w] * DIM + d];
        const float diff = qv - xv;
        tile[d][w] = xv + diff;
        lsum = fmaf(diff, diff, lsum);
    }
    __syncthreads();

    const int w2 = t & 63;
    const int dg = t >> 6;
#pragma unroll
    for (int p = 0; p < 16; ++p) {
        const int d2 = dg * 16 + p;
        out_q[(((size_t)b * DIM + d2) * 64 + h) * 64 + w2] = tile[d2][w2];
    }

    for (int off = 32; off > 0; off >>= 1) lsum += __shfl_down(lsum, off);
    if ((t & 63) == 0) wsum[t >> 6] = lsum;
    __syncthreads();
    if (t == 0) atomicAdd(loss_accum, (wsum[0] + wsum[1]) + (wsum[2] + wsum[3]));
}

__global__ void finalize_kernel(const float* __restrict__ loss_accum,
                                float* __restrict__ out_loss)
{
    out_loss[0] = 0.25f * (loss_accum[0] / 8388608.0f);
}

// ---------------------------------------------------------------------------
extern "C" void kernel_launch(void* const* d_in, const int* in_sizes, int n_in,
                              void* d_out, int out_size, void* d_ws, size_t ws_size,
                              hipStream_t stream)
{
    const float* inputs = (const float*)d_in[0];
    const float* emb_w  = (const float*)d_in[1];
    const float* ema_cs = (const float*)d_in[2];
    const float* ema_w  = (const float*)d_in[3];
    float* out = (float*)d_out;
    float* ws  = (float*)d_ws;

    // ws layout (f32 offsets):
    int*   idxbuf  = (int*)ws;              // [0, 131072)
    float* crep    = ws + 131072;           // [131072, 139264)  16x512
    float* lossac  = ws + 139264;           // [139264]
    float* csbuf   = ws + 139265;           // [139265, 139777)
    float* eebuf   = ws + 139777;           // [139777, 140289)
    float* nemb    = ws + 140289;           // [140289, 173057)
    bfrag* epack   = (bfrag*)(ws + 173060); // 192 KB, 16B-aligned

    // dw replicas (8 MB) in the not-yet-written quantized region of d_out
    // (out+16 -> 64B-aligned); zeroed by argmin, consumed by emaB, then
    // overwritten by quantize.
    float* dwrep = out + 16;

    epack_ee_kernel<<<16, 256, 0, stream>>>(emb_w, epack, eebuf, crep, lossac);

    argmin_mfma_kernel<<<N_VEC / 128, 256, 0, stream>>>(
        inputs, epack, eebuf, idxbuf, crep, dwrep);

    encdw_kernel<<<DW_BLOCKS + ENC_BLOCKS, 256, 0, stream>>>(
        inputs, idxbuf, out + ENC_OFF, dwrep);

    emaA_kernel<<<1, K_CODES, 0, stream>>>(crep, ema_cs, csbuf, out + PERP_OFF);
    emaB_kernel<<<K_CODES * DIM / 256, 256, 0, stream>>>(dwrep, ema_w, csbuf, nemb);

    quantize_kernel<<<QZ_BLOCKS, 256, 0, stream>>>(
        inputs, idxbuf, nemb, out + Q_OFF, lossac);

    finalize_kernel<<<1, 1, 0, stream>>>(lossac, out);
}

// Round 21
// 181.331 us; speedup vs baseline: 1.3297x; 1.0053x over previous
//
#include <hip/hip_runtime.h>

#define DIM 64
#define K_CODES 512
#define N_VEC 131072
#define CREP 16
#define DREP 64
#define Q_OFF 1
#define PERP_OFF 8388609
#define ENC_OFF 8388610

#define DW_BLOCKS 512
#define ENC_BLOCKS 1280
#define QZ_BLOCKS 2048

using bfrag = __attribute__((ext_vector_type(8))) short;  // 8 bf16 = 4 VGPR
using ffrag = __attribute__((ext_vector_type(4))) float;  // 4 f32 acc

// Exact 3-way bf16 truncation split: x == x0 + x1 + x2.
__device__ __forceinline__ void split3(float x, short& h0, short& h1, short& h2)
{
    unsigned u0 = __float_as_uint(x);
    h0 = (short)(u0 >> 16);
    float r = x - __uint_as_float(u0 & 0xFFFF0000u);     // exact
    unsigned u1 = __float_as_uint(r);
    h1 = (short)(u1 >> 16);
    float r2 = r - __uint_as_float(u1 & 0xFFFF0000u);    // exact
    h2 = (short)(__float_as_uint(r2) >> 16);             // r2 fits bf16 exactly
}

// ---------------------------------------------------------------------------
// epack + ee fused, plus zeroing of crep/lossac.
// epack[((ct*2+db)*3+s)*64+lane]: code c = ct*16+(lane&15),
// d = db*32+(lane>>4)*8+0..7, split s. 192 KB, L2-resident.
// ---------------------------------------------------------------------------
__global__ __launch_bounds__(256) void epack_ee_kernel(
    const float* __restrict__ emb_w,
    bfrag* __restrict__ epack,
    float* __restrict__ ee,
    float* __restrict__ crep,
    float* __restrict__ lossac)
{
    __shared__ float part[2][16][8];
    const int tl = threadIdx.x;
    const int t = blockIdx.x * 256 + tl;            // 0..4095
    const int lane = t & 63;
    const int db = (t >> 6) & 1;
    const int ctl = tl >> 7;                        // 0..1 (block-local)
    const int ct = t >> 7;                          // 0..31
    const int r16 = lane & 15, quad = lane >> 4;
    const int c  = ct * 16 + r16;
    const int d0 = db * 32 + quad * 8;
    const float* src = emb_w + (size_t)c * DIM + d0;

    crep[t] = 0.f;
    crep[4096 + t] = 0.f;
    if (t == 0) lossac[0] = 0.f;

    bfrag f0, f1, f2;
    float ssum = 0.f;
#pragma unroll
    for (int j = 0; j < 8; ++j) {
        const float x = src[j];
        ssum = fmaf(x, x, ssum);
        short a, b, cc;
        split3(x, a, b, cc);
        f0[j] = a; f1[j] = b; f2[j] = cc;
    }
    const int base = (ct * 2 + db) * 3;
    epack[(base + 0) * 64 + lane] = f0;
    epack[(base + 1) * 64 + lane] = f1;
    epack[(base + 2) * 64 + lane] = f2;

    part[ctl][r16][db * 4 + quad] = ssum;
    __syncthreads();
    if (tl < 32) {
        const int cl = tl >> 4, r = tl & 15;
        float s = 0.f;
#pragma unroll
        for (int i = 0; i < 8; ++i) s += part[cl][r][i];
        ee[(blockIdx.x * 2 + cl) * 16 + r] = s;
    }
}

// ---------------------------------------------------------------------------
// argmin via 6-pass split-bf16 MFMA. TLP experiment: wave owns 32 vectors
// (2 row-tiles), live set ~110 VGPR, (256,4) -> 4 waves/SIMD (2x the R19
// TLP), grid 1024. Costs 2x epack L2 re-reads; wins if latency-bound.
// Writes idx + counts into 16 replicas; prologue zeroes dwrep slice.
// Tie rule: ascending-k scan + strict <, cross-lane prefers smaller k
// == numpy argmin (first minimum).
// ---------------------------------------------------------------------------
__global__ __launch_bounds__(256, 4) void argmin_mfma_kernel(
    const float* __restrict__ inputs,
    const bfrag* __restrict__ epack,
    const float* __restrict__ eeg,
    int* __restrict__ idx,
    float* __restrict__ counts_rep,
    float* __restrict__ dwrep)
{
    const int t = threadIdx.x;
    const int lane = t & 63;
    const int r16 = lane & 15;
    const int quad = lane >> 4;
    const size_t v0 = (size_t)blockIdx.x * 128 + (t >> 6) * 32;

    // ---- zero this block's 8 KB slice of dwrep (8 MB / 1024 blocks) ----
    {
        float4* z4 = reinterpret_cast<float4*>(dwrep) + (size_t)blockIdx.x * 512;
        const float4 z = make_float4(0.f, 0.f, 0.f, 0.f);
#pragma unroll
        for (int i = 0; i < 2; ++i) z4[i * 256 + t] = z;
    }

    // ---- load + exact-split X into A-fragments (48 VGPRs) ----
    bfrag xf[2][2][3];
#pragma unroll
    for (int rt = 0; rt < 2; ++rt)
#pragma unroll
        for (int db = 0; db < 2; ++db) {
            const float* src = inputs + (v0 + rt * 16 + r16) * DIM + db * 32 + quad * 8;
            const float4 va = *reinterpret_cast<const float4*>(src);
            const float4 vb = *reinterpret_cast<const float4*>(src + 4);
            float vals[8] = {va.x, va.y, va.z, va.w, vb.x, vb.y, vb.z, vb.w};
            bfrag f0, f1, f2;
#pragma unroll
            for (int j = 0; j < 8; ++j) {
                short a, b, c;
                split3(vals[j], a, b, c);
                f0[j] = a; f1[j] = b; f2[j] = c;
            }
            xf[rt][db][0] = f0; xf[rt][db][1] = f1; xf[rt][db][2] = f2;
        }

    float best[2][4];
    int bestk[2][4];
#pragma unroll
    for (int a = 0; a < 2; ++a)
#pragma unroll
        for (int b = 0; b < 4; ++b) { best[a][b] = 3.4e38f; bestk[a][b] = 0; }

    constexpr int PI[6] = {0, 0, 1, 0, 2, 1};
    constexpr int PJ[6] = {0, 1, 0, 2, 0, 1};

#pragma unroll 2
    for (int ct = 0; ct < 32; ++ct) {
        const bfrag* ep = epack + (size_t)ct * 384 + lane;
        bfrag e[2][3];
#pragma unroll
        for (int db = 0; db < 2; ++db)
#pragma unroll
            for (int s = 0; s < 3; ++s)
                e[db][s] = ep[(db * 3 + s) * 64];
        const float eel = eeg[ct * 16 + r16];

        ffrag acc[2];
        acc[0] = (ffrag){0.f, 0.f, 0.f, 0.f};
        acc[1] = (ffrag){0.f, 0.f, 0.f, 0.f};
#pragma unroll
        for (int db = 0; db < 2; ++db)
#pragma unroll
            for (int p = 0; p < 6; ++p) {
                acc[0] = __builtin_amdgcn_mfma_f32_16x16x32_bf16(
                    xf[0][db][PI[p]], e[db][PJ[p]], acc[0], 0, 0, 0);
                acc[1] = __builtin_amdgcn_mfma_f32_16x16x32_bf16(
                    xf[1][db][PI[p]], e[db][PJ[p]], acc[1], 0, 0, 0);
            }

        const int kc = ct * 16 + r16;
#pragma unroll
        for (int rt = 0; rt < 2; ++rt)
#pragma unroll
            for (int rg = 0; rg < 4; ++rg) {
                const float dist = fmaf(-2.f, acc[rt][rg], eel);
                if (dist < best[rt][rg]) { best[rt][rg] = dist; bestk[rt][rg] = kc; }
            }
    }

    // ---- cross-lane argmin over each 16-lane code group ----
#pragma unroll
    for (int rt = 0; rt < 2; ++rt)
#pragma unroll
        for (int rg = 0; rg < 4; ++rg) {
            float b = best[rt][rg];
            int k = bestk[rt][rg];
#pragma unroll
            for (int m = 1; m < 16; m <<= 1) {
                const float ob = __shfl_xor(b, m, 64);
                const int ok = __shfl_xor(k, m, 64);
                if (ob < b || (ob == b && ok < k)) { b = ob; k = ok; }
            }
            bestk[rt][rg] = k;
        }

    if (r16 == 0) {
        float* crep = counts_rep + (blockIdx.x & (CREP - 1)) * K_CODES;
#pragma unroll
        for (int rt = 0; rt < 2; ++rt)
#pragma unroll
            for (int rg = 0; rg < 4; ++rg) {
                const int v = rt * 16 + quad * 4 + rg;
                const int k = bestk[rt][rg];
                idx[v0 + v] = k;
                atomicAdd(&crep[k], 1.0f);
            }
    }
}

// ---------------------------------------------------------------------------
// Uber kernel: enc one-hot full write (1280 blocks, grid-stride float4)
// CONCURRENT with dw segment-sum (512 blocks, 64-replica row atomics).
// ---------------------------------------------------------------------------
__global__ __launch_bounds__(256) void encdw_kernel(
    const float* __restrict__ inputs,
    const int* __restrict__ idx,
    float* __restrict__ enc,
    float* __restrict__ dwrep)
{
    const int bid = blockIdx.x;
    const int t = threadIdx.x;

    if (bid < DW_BLOCKS) {
        __shared__ int sIdx[256];
        const size_t vbase = (size_t)bid * 256;
        sIdx[t] = idx[vbase + t];
        __syncthreads();
        const int w = t >> 6, lane = t & 63;
        const int v0 = w * 64;
#pragma unroll 4
        for (int j = 0; j < 64; ++j) {
            const int v = v0 + j;
            const int k = sIdx[v];
            const float xv = inputs[(vbase + v) * DIM + lane];
            atomicAdd(&dwrep[((size_t)(v & (DREP - 1)) << 15) + (k << 6) + lane], xv);
        }
    } else {
        const int eb = bid - DW_BLOCKS;                    // 0..ENC_BLOCKS-1
        const size_t nf4 = 16777215;                       // (67108864-4)/4
        float4* body = reinterpret_cast<float4*>(enc + 2); // 16B-aligned
        const size_t stride = (size_t)ENC_BLOCKS * 256;

        for (size_t g = (size_t)eb * 256 + t; g < nf4; g += stride) {
            const size_t e0 = 4 * g + 2;                   // element index of .x
            const int r0 = (int)(e0 >> 9);
            const int r1 = (int)((e0 + 3) >> 9);
            const int i0 = idx[r0];
            const int i1 = (r1 != r0) ? idx[r1] : i0;
            float4 v;
            v.x = ((int)(e0 & 511) == i0) ? 1.f : 0.f;
            v.y = ((int)((e0 + 1) & 511) == (((e0 + 1) >> 9) == (size_t)r0 ? i0 : i1)) ? 1.f : 0.f;
            v.z = ((int)((e0 + 2) & 511) == (((e0 + 2) >> 9) == (size_t)r0 ? i0 : i1)) ? 1.f : 0.f;
            v.w = ((int)((e0 + 3) & 511) == (((e0 + 3) >> 9) == (size_t)r0 ? i0 : i1)) ? 1.f : 0.f;
            body[g] = v;
        }

        if (eb == 0 && t == 0) {
            const int k0 = idx[0];
            enc[0] = (k0 == 0) ? 1.f : 0.f;
            enc[1] = (k0 == 1) ? 1.f : 0.f;
            const int kL = idx[N_VEC - 1];
            enc[67108862] = (kL == 510) ? 1.f : 0.f;
            enc[67108863] = (kL == 511) ? 1.f : 0.f;
        }
    }
}

// ---------------------------------------------------------------------------
// emaA: counts replica-reduce + EMA cluster size + Laplace + perplexity.
// ---------------------------------------------------------------------------
__global__ __launch_bounds__(512) void emaA_kernel(
    const float* __restrict__ counts_rep,
    const float* __restrict__ ema_cs,
    float* __restrict__ csbuf,
    float* __restrict__ perp_out)
{
    __shared__ float red[K_CODES];
    const int k = threadIdx.x;
    float cnt = 0.f;
#pragma unroll
    for (int r = 0; r < CREP; ++r) cnt += counts_rep[r * K_CODES + k];
    float cs = ema_cs[k] * 0.99f + 0.01f * cnt;

    red[k] = cs;
    __syncthreads();
    for (int s = K_CODES / 2; s > 0; s >>= 1) {
        if (k < s) red[k] += red[k + s];
        __syncthreads();
    }
    const float n = red[0];
    __syncthreads();

    csbuf[k] = (cs + 1e-5f) / (n + (float)K_CODES * 1e-5f) * n;

    const float p = cnt * (1.0f / (float)N_VEC);
    red[k] = p * logf(p + 1e-10f);
    __syncthreads();
    for (int s = K_CODES / 2; s > 0; s >>= 1) {
        if (k < s) red[k] += red[k + s];
        __syncthreads();
    }
    if (k == 0) perp_out[0] = expf(-red[0]);
}

// ---------------------------------------------------------------------------
// emaB: dw replica-reduce + codebook update. 32768 (k,d) threads.
// ---------------------------------------------------------------------------
__global__ __launch_bounds__(256) void emaB_kernel(
    const float* __restrict__ dwrep,
    const float* __restrict__ ema_w,
    const float* __restrict__ csbuf,
    float* __restrict__ new_emb)
{
    const int t = blockIdx.x * 256 + threadIdx.x;   // 0..32767 = k*64+d
    const int k = t >> 6;
    float dwv = 0.f;
#pragma unroll
    for (int r = 0; r < DREP; ++r) dwv += dwrep[((size_t)r << 15) + t];
    const float v = ema_w[t] * 0.99f + 0.01f * dwv;
    new_emb[t] = v / csbuf[k];
}

// ---------------------------------------------------------------------------
// quantize: gather + straight-through + NHWC->NCHW + commitment loss.
// ---------------------------------------------------------------------------
__global__ __launch_bounds__(256) void quantize_kernel(
    const float* __restrict__ inputs,
    const int* __restrict__ idx,
    const float* __restrict__ new_emb,
    float* __restrict__ out_q,
    float* __restrict__ loss_accum)
{
    __shared__ int sIdx[64];
    __shared__ float tile[DIM][65];
    __shared__ float wsum[4];

    const int bh = blockIdx.x;
    const int b = bh >> 6, h = bh & 63;
    const int t = threadIdx.x;

    if (t < 64) sIdx[t] = idx[bh * 64 + t];
    __syncthreads();

    const float* inRow = inputs + (size_t)bh * 64 * DIM;
    const int d = t & 63;
    const int wg = t >> 6;
    float lsum = 0.f;
#pragma unroll
    for (int p = 0; p < 16; ++p) {
        const int w = wg * 16 + p;
        const float xv = inRow[w * DIM + d];
        const float qv = new_emb[sIdx[w] * DIM + d];
        const float diff = qv - xv;
        tile[d][w] = xv + diff;
        lsum = fmaf(diff, diff, lsum);
    }
    __syncthreads();

    const int w2 = t & 63;
    const int dg = t >> 6;
#pragma unroll
    for (int p = 0; p < 16; ++p) {
        const int d2 = dg * 16 + p;
        out_q[(((size_t)b * DIM + d2) * 64 + h) * 64 + w2] = tile[d2][w2];
    }

    for (int off = 32; off > 0; off >>= 1) lsum += __shfl_down(lsum, off);
    if ((t & 63) == 0) wsum[t >> 6] = lsum;
    __syncthreads();
    if (t == 0) atomicAdd(loss_accum, (wsum[0] + wsum[1]) + (wsum[2] + wsum[3]));
}

__global__ void finalize_kernel(const float* __restrict__ loss_accum,
                                float* __restrict__ out_loss)
{
    out_loss[0] = 0.25f * (loss_accum[0] / 8388608.0f);
}

// ---------------------------------------------------------------------------
extern "C" void kernel_launch(void* const* d_in, const int* in_sizes, int n_in,
                              void* d_out, int out_size, void* d_ws, size_t ws_size,
                              hipStream_t stream)
{
    const float* inputs = (const float*)d_in[0];
    const float* emb_w  = (const float*)d_in[1];
    const float* ema_cs = (const float*)d_in[2];
    const float* ema_w  = (const float*)d_in[3];
    float* out = (float*)d_out;
    float* ws  = (float*)d_ws;

    // ws layout (f32 offsets):
    int*   idxbuf  = (int*)ws;              // [0, 131072)
    float* crep    = ws + 131072;           // [131072, 139264)  16x512
    float* lossac  = ws + 139264;           // [139264]
    float* csbuf   = ws + 139265;           // [139265, 139777)
    float* eebuf   = ws + 139777;           // [139777, 140289)
    float* nemb    = ws + 140289;           // [140289, 173057)
    bfrag* epack   = (bfrag*)(ws + 173060); // 192 KB, 16B-aligned

    // dw replicas (8 MB) in the not-yet-written quantized region of d_out
    // (out+16 -> 64B-aligned); zeroed by argmin, consumed by emaB, then
    // overwritten by quantize.
    float* dwrep = out + 16;

    epack_ee_kernel<<<16, 256, 0, stream>>>(emb_w, epack, eebuf, crep, lossac);

    argmin_mfma_kernel<<<N_VEC / 128, 256, 0, stream>>>(
        inputs, epack, eebuf, idxbuf, crep, dwrep);

    encdw_kernel<<<DW_BLOCKS + ENC_BLOCKS, 256, 0, stream>>>(
        inputs, idxbuf, out + ENC_OFF, dwrep);

    emaA_kernel<<<1, K_CODES, 0, stream>>>(crep, ema_cs, csbuf, out + PERP_OFF);
    emaB_kernel<<<K_CODES * DIM / 256, 256, 0, stream>>>(dwrep, ema_w, csbuf, nemb);

    quantize_kernel<<<QZ_BLOCKS, 256, 0, stream>>>(
        inputs, idxbuf, nemb, out + Q_OFF, lossac);

    finalize_kernel<<<1, 1, 0, stream>>>(lossac, out);
}